// Round 7
// baseline (206.824 us; speedup 1.0000x reference)
//
#include <hip/hip_runtime.h>

#define HH 96
#define WW 96
#define HW 9216
#define NB 8

typedef __bf16 bf16x8 __attribute__((ext_vector_type(8)));
typedef float  f32x4  __attribute__((ext_vector_type(4)));

union BF8 { uint4 u; bf16x8 v; unsigned short s[8]; };

__device__ __forceinline__ unsigned short f2bf_bits(float f) {
    unsigned u = __float_as_uint(f);
    unsigned r = u + 0x7FFFu + ((u >> 16) & 1u);     // RNE
    return (unsigned short)(r >> 16);
}
__device__ __forceinline__ float bf2f(unsigned short s) {
    return __uint_as_float(((unsigned)s) << 16);
}

// ---------------------------------------------------------------------------
// Kernel 1: x NCHW fp32 -> xt NHWC bf16 (unchanged). Blocks < 216 also build
// wTb [tap][co][c] bf16 and owTb [j(32)][tap*64+c] bf16.
// ---------------------------------------------------------------------------
__global__ __launch_bounds__(256) void xcvt_prep(const float* __restrict__ x,
                                                 const float* __restrict__ weight,
                                                 const float* __restrict__ off_w,
                                                 unsigned short* __restrict__ xt,
                                                 unsigned short* __restrict__ wTb,
                                                 unsigned short* __restrict__ owTb) {
    __shared__ unsigned short T[64 * 72];   // [px][c], pad 72
    int bid   = blockIdx.x;                 // 1152
    int t     = threadIdx.x;
    int b     = bid & 7;                    // XCD-affine
    int pbase = (bid >> 3) * 64;
    int pl    = t & 63;
    int q     = t >> 6;                     // c-group 0..3

    const float* xp = x + ((size_t)(b * 64 + q * 16)) * HW + pbase + pl;
    unsigned short hb[16];
#pragma unroll
    for (int i = 0; i < 16; ++i) hb[i] = f2bf_bits(xp[(size_t)i * HW]);

    uint4 w0, w1;
    w0.x = hb[0]  | (hb[1]  << 16); w0.y = hb[2]  | (hb[3]  << 16);
    w0.z = hb[4]  | (hb[5]  << 16); w0.w = hb[6]  | (hb[7]  << 16);
    w1.x = hb[8]  | (hb[9]  << 16); w1.y = hb[10] | (hb[11] << 16);
    w1.z = hb[12] | (hb[13] << 16); w1.w = hb[14] | (hb[15] << 16);
    *(uint4*)&T[pl * 72 + q * 16]     = w0;
    *(uint4*)&T[pl * 72 + q * 16 + 8] = w1;
    __syncthreads();

    uint4 a  = *(const uint4*)&T[(t >> 2) * 72 + (t & 3) * 16];
    uint4 b2 = *(const uint4*)&T[(t >> 2) * 72 + (t & 3) * 16 + 8];
    unsigned short* dst = xt + ((size_t)(b * HW + pbase)) * 64 + t * 16;
    *(uint4*)dst       = a;
    *(uint4*)(dst + 8) = b2;

    if (bid < 216) {                        // 216*256 = 36864 + 18432
        int i = bid * 256 + t;
        if (i < 36864) {
            int tap = i >> 12;
            int co  = (i >> 6) & 63;
            int c   = i & 63;
            wTb[i] = f2bf_bits(weight[(co * 64 + c) * 9 + tap]);
        } else {
            int f   = i - 36864;            // f < 18432 = 32*576
            int j   = f / 576;
            int kk  = f - j * 576;
            int tap = kk >> 6;
            int c   = kk & 63;
            owTb[f] = (j < 18) ? f2bf_bits(off_w[(j * 64 + c) * 9 + tap]) : (unsigned short)0;
        }
    }
}

// ---------------------------------------------------------------------------
// Kernel 2 (fused): identical structure to R6, but tap loops are ROLLED
// (#pragma unroll 1). R5/R6's full unroll produced ~40 KB straight-line code
// > 32 KB I$ -> instruction-fetch-latency-bound (VALUBusy 12.6%, invariant
// to occupancy). Rolled body ~3.6 KB keeps the whole hot loop I$-resident.
// ---------------------------------------------------------------------------
__global__ __launch_bounds__(256) void deform_fused(const unsigned short* __restrict__ xt,
                                                    const unsigned short* __restrict__ wTb,
                                                    const unsigned short* __restrict__ owTb,
                                                    const float* __restrict__ bias,
                                                    const float* __restrict__ ob,
                                                    float* __restrict__ out) {
    __shared__ float offs[4 * 16 * 20];     // per-wave [16 px][18+pad j]

    int bid   = blockIdx.x;                 // 1152
    int t     = threadIdx.x;
    int b     = bid & 7;                    // image per XCD
    int wv    = t >> 6;                     // wave 0..3
    int l     = t & 63;
    int ln    = l & 15;                     // m-row = local pixel
    int qd    = l >> 4;                     // k-chunk (8 channels)
    int pbase = (bid >> 3) * 64 + wv * 16;  // this wave's 16-px tile

    int px = pbase + ln;
    int h  = px / WW;
    int w  = px - h * WW;

    const unsigned short* xb = xt + (size_t)b * HW * 64;
    float* offw = &offs[wv * 320];

    // ---- phase A: offsets[18] for the tile via MFMA (rolled) ----
    f32x4 aj0 = {0.f, 0.f, 0.f, 0.f};
    f32x4 aj1 = {0.f, 0.f, 0.f, 0.f};
#pragma unroll 1
    for (int tap = 0; tap < 9; ++tap) {
        int  r  = tap / 3, s = tap - r * 3;
        int  iy = h - 1 + r, ix = w - 1 + s;
        bool valid = (iy >= 0) & (iy < HH) & (ix >= 0) & (ix < WW);
        int  cy = min(max(iy, 0), HH - 1), cx = min(max(ix, 0), WW - 1);
        const unsigned short* pp = xb + ((size_t)(cy * WW + cx)) * 64 + qd * 8;
        BF8 a0, a1;
        a0.u = *(const uint4*)pp;
        a1.u = *(const uint4*)(pp + 32);
        if (!valid) {
            a0.u = make_uint4(0u, 0u, 0u, 0u);
            a1.u = make_uint4(0u, 0u, 0u, 0u);
        }
        const unsigned short* br0 = owTb + (size_t)ln * 576 + tap * 64 + qd * 8;
        const unsigned short* br1 = owTb + (size_t)(16 + ln) * 576 + tap * 64 + qd * 8;
        aj0 = __builtin_amdgcn_mfma_f32_16x16x32_bf16(a0.v, *(const bf16x8*)br0,        aj0, 0, 0, 0);
        aj0 = __builtin_amdgcn_mfma_f32_16x16x32_bf16(a1.v, *(const bf16x8*)(br0 + 32), aj0, 0, 0, 0);
        aj1 = __builtin_amdgcn_mfma_f32_16x16x32_bf16(a0.v, *(const bf16x8*)br1,        aj1, 0, 0, 0);
        aj1 = __builtin_amdgcn_mfma_f32_16x16x32_bf16(a1.v, *(const bf16x8*)(br1 + 32), aj1, 0, 0, 0);
    }
    // transpose D (col=j, row=px) -> offs[px][j]
    {
        float obj = ob[ln];
#pragma unroll
        for (int rg = 0; rg < 4; ++rg) offw[(qd * 4 + rg) * 20 + ln] = aj0[rg] + obj;
        if (ln < 2) {
            float obj1 = ob[16 + ln];
#pragma unroll
            for (int rg = 0; rg < 4; ++rg) offw[(qd * 4 + rg) * 20 + 16 + ln] = aj1[rg] + obj1;
        }
    }
    __syncthreads();

    float offy[9], offx[9];
#pragma unroll
    for (int k = 0; k < 9; ++k) {
        offy[k] = offw[ln * 20 + 2 * k];
        offx[k] = offw[ln * 20 + 2 * k + 1];
    }

    // ---- phase B: sample + main MFMA (rolled tap loop) ----
    f32x4 acc[4] = {{0.f,0.f,0.f,0.f},{0.f,0.f,0.f,0.f},{0.f,0.f,0.f,0.f},{0.f,0.f,0.f,0.f}};

#pragma unroll 1
    for (int tap = 0; tap < 9; ++tap) {
        int   r = tap / 3, s = tap - r * 3;
        float sy = (float)(h + r) + offy[tap];
        float sx = (float)(w + s) + offx[tap];
        float fy = floorf(sy), fx = floorf(sx);
        int   y0 = (int)fy, x0 = (int)fx;
        int   y1 = y0 + 1, x1 = x0 + 1;
        float wy1 = sy - fy, wx1 = sx - fx;
        float wy0 = 1.f - wy1, wx0 = 1.f - wx1;

        float m00 = (y0 >= 0 && y0 < HH && x0 >= 0 && x0 < WW) ? 1.f : 0.f;
        float m01 = (y0 >= 0 && y0 < HH && x1 >= 0 && x1 < WW) ? 1.f : 0.f;
        float m10 = (y1 >= 0 && y1 < HH && x0 >= 0 && x0 < WW) ? 1.f : 0.f;
        float m11 = (y1 >= 0 && y1 < HH && x1 >= 0 && x1 < WW) ? 1.f : 0.f;

        int cy0 = min(max(y0, 0), HH - 1), cy1 = min(max(y1, 0), HH - 1);
        int cx0 = min(max(x0, 0), WW - 1), cx1 = min(max(x1, 0), WW - 1);
        float w00 = wy0 * wx0 * m00, w01 = wy0 * wx1 * m01;
        float w10 = wy1 * wx0 * m10, w11 = wy1 * wx1 * m11;

        const unsigned short* p00 = xb + ((size_t)(cy0 * WW + cx0)) * 64 + qd * 8;
        const unsigned short* p01 = xb + ((size_t)(cy0 * WW + cx1)) * 64 + qd * 8;
        const unsigned short* p10 = xb + ((size_t)(cy1 * WW + cx0)) * 64 + qd * 8;
        const unsigned short* p11 = xb + ((size_t)(cy1 * WW + cx1)) * 64 + qd * 8;

        BF8 c00a, c00b, c01a, c01b, c10a, c10b, c11a, c11b;
        c00a.u = *(const uint4*)p00;  c00b.u = *(const uint4*)(p00 + 32);
        c01a.u = *(const uint4*)p01;  c01b.u = *(const uint4*)(p01 + 32);
        c10a.u = *(const uint4*)p10;  c10b.u = *(const uint4*)(p10 + 32);
        c11a.u = *(const uint4*)p11;  c11b.u = *(const uint4*)(p11 + 32);

        BF8 A0, A1;                   // A-frag: pixel ln, channels qd*8..(+32)
#pragma unroll
        for (int i = 0; i < 8; ++i) {
            float v0 = w00 * bf2f(c00a.s[i]) + w01 * bf2f(c01a.s[i])
                     + w10 * bf2f(c10a.s[i]) + w11 * bf2f(c11a.s[i]);
            float v1 = w00 * bf2f(c00b.s[i]) + w01 * bf2f(c01b.s[i])
                     + w10 * bf2f(c10b.s[i]) + w11 * bf2f(c11b.s[i]);
            A0.s[i] = f2bf_bits(v0);
            A1.s[i] = f2bf_bits(v1);
        }

#pragma unroll
        for (int ct = 0; ct < 4; ++ct) {
            const unsigned short* wrow = wTb + (size_t)tap * 4096 + (ct * 16 + ln) * 64 + qd * 8;
            acc[ct] = __builtin_amdgcn_mfma_f32_16x16x32_bf16(A0.v, *(const bf16x8*)wrow,        acc[ct], 0, 0, 0);
            acc[ct] = __builtin_amdgcn_mfma_f32_16x16x32_bf16(A1.v, *(const bf16x8*)(wrow + 32), acc[ct], 0, 0, 0);
        }
    }

    // ---- epilogue: D col=co (ln), rows px = qd*4+reg -> float4 stores ----
#pragma unroll
    for (int ct = 0; ct < 4; ++ct) {
        int   co = ct * 16 + ln;
        float bv = bias[co];
        float4 st;
        st.x = acc[ct][0] + bv; st.y = acc[ct][1] + bv;
        st.z = acc[ct][2] + bv; st.w = acc[ct][3] + bv;
        *(float4*)(out + ((size_t)(b * 64 + co)) * HW + pbase + qd * 4) = st;
    }
}

// ---------------------------------------------------------------------------
extern "C" void kernel_launch(void* const* d_in, const int* in_sizes, int n_in,
                              void* d_out, int out_size, void* d_ws, size_t ws_size,
                              hipStream_t stream) {
    const float* x      = (const float*)d_in[0];   // 8*64*96*96
    const float* weight = (const float*)d_in[1];   // 64*64*3*3
    const float* bias   = (const float*)d_in[2];   // 64
    const float* off_w  = (const float*)d_in[3];   // 18*64*3*3
    const float* off_b  = (const float*)d_in[4];   // 18
    float* out = (float*)d_out;

    unsigned short* xt   = (unsigned short*)d_ws;  // 4,718,592 bf16
    unsigned short* wTb  = xt + 4718592;           // 36,864 bf16
    unsigned short* owTb = wTb + 36864;            // 18,432 bf16

    hipLaunchKernelGGL(xcvt_prep,    dim3(1152), dim3(256), 0, stream,
                       x, weight, off_w, xt, wTb, owTb);
    hipLaunchKernelGGL(deform_fused, dim3(1152), dim3(256), 0, stream,
                       xt, wTb, owTb, bias, off_b, out);
}

// Round 8
// 163.186 us; speedup vs baseline: 1.2674x; 1.2674x over previous
//
#include <hip/hip_runtime.h>

#define HH 96
#define WW 96
#define HW 9216
#define NB 8

typedef __bf16 bf16x8 __attribute__((ext_vector_type(8)));
typedef float  f32x4  __attribute__((ext_vector_type(4)));

union BF8 { uint4 u; bf16x8 v; unsigned short s[8]; };

__device__ __forceinline__ unsigned short f2bf_bits(float f) {
    unsigned u = __float_as_uint(f);
    unsigned r = u + 0x7FFFu + ((u >> 16) & 1u);     // RNE
    return (unsigned short)(r >> 16);
}
__device__ __forceinline__ float bf2f(unsigned short s) {
    return __uint_as_float(((unsigned)s) << 16);
}

// ---------------------------------------------------------------------------
// Kernel 1: x NCHW fp32 -> xt NHWC bf16. Blocks < 216 also build
// wTb [tap][co][c] bf16 and owTb [j(32)][tap*64+c] bf16. (unchanged)
// ---------------------------------------------------------------------------
__global__ __launch_bounds__(256) void xcvt_prep(const float* __restrict__ x,
                                                 const float* __restrict__ weight,
                                                 const float* __restrict__ off_w,
                                                 unsigned short* __restrict__ xt,
                                                 unsigned short* __restrict__ wTb,
                                                 unsigned short* __restrict__ owTb) {
    __shared__ unsigned short T[64 * 72];
    int bid   = blockIdx.x;                 // 1152
    int t     = threadIdx.x;
    int b     = bid & 7;
    int pbase = (bid >> 3) * 64;
    int pl    = t & 63;
    int q     = t >> 6;

    const float* xp = x + ((size_t)(b * 64 + q * 16)) * HW + pbase + pl;
    unsigned short hb[16];
#pragma unroll
    for (int i = 0; i < 16; ++i) hb[i] = f2bf_bits(xp[(size_t)i * HW]);

    uint4 w0, w1;
    w0.x = hb[0]  | (hb[1]  << 16); w0.y = hb[2]  | (hb[3]  << 16);
    w0.z = hb[4]  | (hb[5]  << 16); w0.w = hb[6]  | (hb[7]  << 16);
    w1.x = hb[8]  | (hb[9]  << 16); w1.y = hb[10] | (hb[11] << 16);
    w1.z = hb[12] | (hb[13] << 16); w1.w = hb[14] | (hb[15] << 16);
    *(uint4*)&T[pl * 72 + q * 16]     = w0;
    *(uint4*)&T[pl * 72 + q * 16 + 8] = w1;
    __syncthreads();

    uint4 a  = *(const uint4*)&T[(t >> 2) * 72 + (t & 3) * 16];
    uint4 b2 = *(const uint4*)&T[(t >> 2) * 72 + (t & 3) * 16 + 8];
    unsigned short* dst = xt + ((size_t)(b * HW + pbase)) * 64 + t * 16;
    *(uint4*)dst       = a;
    *(uint4*)(dst + 8) = b2;

    if (bid < 216) {
        int i = bid * 256 + t;
        if (i < 36864) {
            int tap = i >> 12;
            int co  = (i >> 6) & 63;
            int c   = i & 63;
            wTb[i] = f2bf_bits(weight[(co * 64 + c) * 9 + tap]);
        } else {
            int f   = i - 36864;
            int j   = f / 576;
            int kk  = f - j * 576;
            int tap = kk >> 6;
            int c   = kk & 63;
            owTb[f] = (j < 18) ? f2bf_bits(off_w[(j * 64 + c) * 9 + tap]) : (unsigned short)0;
        }
    }
}

// ---------------------------------------------------------------------------
// Kernel 2: offset conv (R4 structure + cross-tap register prefetch).
// ---------------------------------------------------------------------------
__global__ __launch_bounds__(256) void offs_mfma(const unsigned short* __restrict__ xt,
                                                 const unsigned short* __restrict__ owTb,
                                                 const float* __restrict__ ob,
                                                 float* __restrict__ off) {
    __shared__ unsigned short S[64 * 72];

    int bid   = blockIdx.x;                 // 1152
    int t     = threadIdx.x;
    int b     = bid & 7;
    int pbase = (bid >> 3) * 64;

    int pl = t & 63;
    int cg = t >> 6;
    int px = pbase + pl;
    int h  = px / WW;
    int w  = px - h * WW;

    int ln = t & 15;
    int qd = (t >> 4) & 3;
    int pt = t >> 6;

    f32x4 accj[2] = {{0.f, 0.f, 0.f, 0.f}, {0.f, 0.f, 0.f, 0.f}};

    const unsigned short* xb = xt + (size_t)b * HW * 64;

    // pipeline registers: patch (cur/nxt) + B-rows (cur/nxt)
    uint4 pa, pb, paN, pbN;
    uint4 br00, br01, br10, br11, br00N, br01N, br10N, br11N;

    // ---- issue tap 0 ----
    {
        int  iy = h - 1, ix = w - 1;
        bool valid = (iy >= 0) & (ix >= 0);
        int  cy = max(iy, 0), cx = max(ix, 0);
        const uint4* p = (const uint4*)(xb + ((size_t)(cy * WW + cx)) * 64 + cg * 16);
        pa = p[0]; pb = p[1];
        if (!valid) { pa = make_uint4(0,0,0,0); pb = make_uint4(0,0,0,0); }
        const unsigned short* b0p = owTb + (size_t)ln * 576 + qd * 8;
        const unsigned short* b1p = owTb + (size_t)(16 + ln) * 576 + qd * 8;
        br00 = *(const uint4*)b0p;  br01 = *(const uint4*)(b0p + 32);
        br10 = *(const uint4*)b1p;  br11 = *(const uint4*)(b1p + 32);
    }

    for (int tap = 0; tap < 9; ++tap) {
        // ---- issue tap+1 ----
        if (tap < 8) {
            int  tn = tap + 1;
            int  r  = tn / 3, s = tn - r * 3;
            int  iy = h - 1 + r, ix = w - 1 + s;
            bool valid = (iy >= 0) & (iy < HH) & (ix >= 0) & (ix < WW);
            int  cy = min(max(iy, 0), HH - 1), cx = min(max(ix, 0), WW - 1);
            const uint4* p = (const uint4*)(xb + ((size_t)(cy * WW + cx)) * 64 + cg * 16);
            paN = p[0]; pbN = p[1];
            if (!valid) { paN = make_uint4(0,0,0,0); pbN = make_uint4(0,0,0,0); }
            const unsigned short* b0p = owTb + (size_t)ln * 576 + tn * 64 + qd * 8;
            const unsigned short* b1p = owTb + (size_t)(16 + ln) * 576 + tn * 64 + qd * 8;
            br00N = *(const uint4*)b0p;  br01N = *(const uint4*)(b0p + 32);
            br10N = *(const uint4*)b1p;  br11N = *(const uint4*)(b1p + 32);
        }

        // ---- consume current: stage patch to LDS ----
        *(uint4*)&S[pl * 72 + cg * 16]     = pa;
        *(uint4*)&S[pl * 72 + cg * 16 + 8] = pb;
        __syncthreads();

        BF8 a0, a1, u00, u01, u10, u11;
        a0.u = *(const uint4*)&S[(pt * 16 + ln) * 72 + qd * 8];
        a1.u = *(const uint4*)&S[(pt * 16 + ln) * 72 + 32 + qd * 8];
        u00.u = br00; u01.u = br01; u10.u = br10; u11.u = br11;
        accj[0] = __builtin_amdgcn_mfma_f32_16x16x32_bf16(a0.v, u00.v, accj[0], 0, 0, 0);
        accj[0] = __builtin_amdgcn_mfma_f32_16x16x32_bf16(a1.v, u01.v, accj[0], 0, 0, 0);
        accj[1] = __builtin_amdgcn_mfma_f32_16x16x32_bf16(a0.v, u10.v, accj[1], 0, 0, 0);
        accj[1] = __builtin_amdgcn_mfma_f32_16x16x32_bf16(a1.v, u11.v, accj[1], 0, 0, 0);
        __syncthreads();

        pa = paN; pb = pbN;
        br00 = br00N; br01 = br01N; br10 = br10N; br11 = br11N;
    }

    // epilogue: D col = j, row = px (quad*4 + reg)
    int pxo = pbase + pt * 16 + qd * 4;
    {
        float bv = ob[ln];
        float4 st;
        st.x = accj[0].x + bv; st.y = accj[0].y + bv;
        st.z = accj[0].z + bv; st.w = accj[0].w + bv;
        *(float4*)(off + ((size_t)(b * 18 + ln)) * HW + pxo) = st;
    }
    if (ln < 2) {
        int   j  = 16 + ln;
        float bv = ob[j];
        float4 st;
        st.x = accj[1].x + bv; st.y = accj[1].y + bv;
        st.z = accj[1].z + bv; st.w = accj[1].w + bv;
        *(float4*)(off + ((size_t)(b * 18 + j)) * HW + pxo) = st;
    }
}

// ---------------------------------------------------------------------------
// Kernel 3: deformable main (R4 structure + cross-tap register prefetch).
// ---------------------------------------------------------------------------
__global__ __launch_bounds__(256) void deform_main(const unsigned short* __restrict__ xt,
                                                   const unsigned short* __restrict__ wTb,
                                                   const float* __restrict__ bias,
                                                   const float* __restrict__ off,
                                                   float* __restrict__ out) {
    __shared__ unsigned short S[64 * 72];   // [px][c]
    __shared__ unsigned short Wk[64 * 72];  // [co][c]

    int bid   = blockIdx.x;                 // 1152
    int t     = threadIdx.x;
    int b     = bid & 7;
    int pbase = (bid >> 3) * 64;

    int pl = t & 63;
    int cg = t >> 6;
    int px = pbase + pl;
    int h  = px / WW;
    int w  = px - h * WW;

    int ln = t & 15;
    int qd = (t >> 4) & 3;
    int ct = t >> 6;

    const unsigned short* xb = xt + (size_t)b * HW * 64;
    const float* offb = off + (size_t)b * 18 * HW + px;

    float offy[9], offx[9];
#pragma unroll
    for (int k = 0; k < 9; ++k) {
        offy[k] = offb[(2 * k) * HW];
        offx[k] = offb[(2 * k + 1) * HW];
    }

    f32x4 acc[4] = {{0.f,0.f,0.f,0.f},{0.f,0.f,0.f,0.f},{0.f,0.f,0.f,0.f},{0.f,0.f,0.f,0.f}};

    // pipeline registers: 8 corner uint4 + 2 weight uint4 + 4 bilinear weights
    uint4 c00a, c00b, c01a, c01b, c10a, c10b, c11a, c11b, wk0, wk1;
    uint4 c00aN, c00bN, c01aN, c01bN, c10aN, c10bN, c11aN, c11bN, wk0N, wk1N;
    float w00, w01, w10, w11, w00N, w01N, w10N, w11N;

#define ISSUE_TAP(TAP, A00,B00,A01,B01,A10,B10,A11,B11, WA,WB, W0,W1,W2,W3)            \
    {                                                                                   \
        int   r = (TAP) / 3, s = (TAP) - r * 3;                                         \
        float sy = (float)(h + r) + offy[(TAP)];                                        \
        float sx = (float)(w + s) + offx[(TAP)];                                        \
        float fy = floorf(sy), fx = floorf(sx);                                         \
        int   y0 = (int)fy, x0 = (int)fx;                                               \
        int   y1 = y0 + 1, x1 = x0 + 1;                                                 \
        float wy1 = sy - fy, wx1 = sx - fx;                                             \
        float wy0 = 1.f - wy1, wx0 = 1.f - wx1;                                         \
        float m00 = (y0 >= 0 && y0 < HH && x0 >= 0 && x0 < WW) ? 1.f : 0.f;             \
        float m01 = (y0 >= 0 && y0 < HH && x1 >= 0 && x1 < WW) ? 1.f : 0.f;             \
        float m10 = (y1 >= 0 && y1 < HH && x0 >= 0 && x0 < WW) ? 1.f : 0.f;             \
        float m11 = (y1 >= 0 && y1 < HH && x1 >= 0 && x1 < WW) ? 1.f : 0.f;             \
        int cy0 = min(max(y0, 0), HH - 1), cy1 = min(max(y1, 0), HH - 1);               \
        int cx0 = min(max(x0, 0), WW - 1), cx1 = min(max(x1, 0), WW - 1);               \
        W0 = wy0 * wx0 * m00; W1 = wy0 * wx1 * m01;                                     \
        W2 = wy1 * wx0 * m10; W3 = wy1 * wx1 * m11;                                     \
        const uint4* p00 = (const uint4*)(xb + ((size_t)(cy0 * WW + cx0)) * 64 + cg * 16); \
        const uint4* p01 = (const uint4*)(xb + ((size_t)(cy0 * WW + cx1)) * 64 + cg * 16); \
        const uint4* p10 = (const uint4*)(xb + ((size_t)(cy1 * WW + cx0)) * 64 + cg * 16); \
        const uint4* p11 = (const uint4*)(xb + ((size_t)(cy1 * WW + cx1)) * 64 + cg * 16); \
        A00 = p00[0]; B00 = p00[1];                                                     \
        A01 = p01[0]; B01 = p01[1];                                                     \
        A10 = p10[0]; B10 = p10[1];                                                     \
        A11 = p11[0]; B11 = p11[1];                                                     \
        const uint4* wsrc = (const uint4*)(wTb + (size_t)(TAP) * 4096);                 \
        WA = wsrc[2 * t]; WB = wsrc[2 * t + 1];                                         \
    }

    // ---- issue tap 0 ----
    ISSUE_TAP(0, c00a,c00b,c01a,c01b,c10a,c10b,c11a,c11b, wk0,wk1, w00,w01,w10,w11);

    for (int tap = 0; tap < 9; ++tap) {
        // ---- issue tap+1 (loads fly across consume + barriers + MFMA) ----
        if (tap < 8) {
            ISSUE_TAP(tap + 1, c00aN,c00bN,c01aN,c01bN,c10aN,c10bN,c11aN,c11bN,
                      wk0N,wk1N, w00N,w01N,w10N,w11N);
        }

        // ---- consume current tap: bilinear -> S (bf16), Wk stage ----
        {
            BF8 q00a, q00b, q01a, q01b, q10a, q10b, q11a, q11b;
            q00a.u = c00a; q00b.u = c00b; q01a.u = c01a; q01b.u = c01b;
            q10a.u = c10a; q10b.u = c10b; q11a.u = c11a; q11b.u = c11b;
            unsigned short ov[16];
#pragma unroll
            for (int i = 0; i < 8; ++i) {
                float v0 = w00 * bf2f(q00a.s[i]) + w01 * bf2f(q01a.s[i])
                         + w10 * bf2f(q10a.s[i]) + w11 * bf2f(q11a.s[i]);
                float v1 = w00 * bf2f(q00b.s[i]) + w01 * bf2f(q01b.s[i])
                         + w10 * bf2f(q10b.s[i]) + w11 * bf2f(q11b.s[i]);
                ov[i]     = f2bf_bits(v0);
                ov[8 + i] = f2bf_bits(v1);
            }
            uint4 s0, s1;
            s0.x = ov[0]  | (ov[1]  << 16); s0.y = ov[2]  | (ov[3]  << 16);
            s0.z = ov[4]  | (ov[5]  << 16); s0.w = ov[6]  | (ov[7]  << 16);
            s1.x = ov[8]  | (ov[9]  << 16); s1.y = ov[10] | (ov[11] << 16);
            s1.z = ov[12] | (ov[13] << 16); s1.w = ov[14] | (ov[15] << 16);
            *(uint4*)&S[pl * 72 + cg * 16]     = s0;
            *(uint4*)&S[pl * 72 + cg * 16 + 8] = s1;

            int co = t >> 2, c0 = (t & 3) * 16;
            *(uint4*)&Wk[co * 72 + c0]     = wk0;
            *(uint4*)&Wk[co * 72 + c0 + 8] = wk1;
        }
        __syncthreads();

        // ---- MFMA: wave ct covers co-tile ct, all 4 px-tiles ----
        {
            BF8 b0, b1;
            b0.u = *(const uint4*)&Wk[(ct * 16 + ln) * 72 + qd * 8];
            b1.u = *(const uint4*)&Wk[(ct * 16 + ln) * 72 + 32 + qd * 8];
#pragma unroll
            for (int pt = 0; pt < 4; ++pt) {
                BF8 a0, a1;
                a0.u = *(const uint4*)&S[(pt * 16 + ln) * 72 + qd * 8];
                a1.u = *(const uint4*)&S[(pt * 16 + ln) * 72 + 32 + qd * 8];
                acc[pt] = __builtin_amdgcn_mfma_f32_16x16x32_bf16(a0.v, b0.v, acc[pt], 0, 0, 0);
                acc[pt] = __builtin_amdgcn_mfma_f32_16x16x32_bf16(a1.v, b1.v, acc[pt], 0, 0, 0);
            }
        }
        __syncthreads();

        // rotate pipeline
        c00a = c00aN; c00b = c00bN; c01a = c01aN; c01b = c01bN;
        c10a = c10aN; c10b = c10bN; c11a = c11aN; c11b = c11bN;
        wk0 = wk0N; wk1 = wk1N;
        w00 = w00N; w01 = w01N; w10 = w10N; w11 = w11N;
    }
#undef ISSUE_TAP

    // ---- epilogue: D col=co, rows px = qd*4+reg ----
    int   co = ct * 16 + ln;
    float bv = bias[co];
    float* ob2 = out + ((size_t)(b * 64 + co)) * HW + pbase + qd * 4;
#pragma unroll
    for (int pt = 0; pt < 4; ++pt) {
        float4 st;
        st.x = acc[pt].x + bv; st.y = acc[pt].y + bv;
        st.z = acc[pt].z + bv; st.w = acc[pt].w + bv;
        *(float4*)(ob2 + pt * 16) = st;
    }
}

// ---------------------------------------------------------------------------
extern "C" void kernel_launch(void* const* d_in, const int* in_sizes, int n_in,
                              void* d_out, int out_size, void* d_ws, size_t ws_size,
                              hipStream_t stream) {
    const float* x      = (const float*)d_in[0];   // 8*64*96*96
    const float* weight = (const float*)d_in[1];   // 64*64*3*3
    const float* bias   = (const float*)d_in[2];   // 64
    const float* off_w  = (const float*)d_in[3];   // 18*64*3*3
    const float* off_b  = (const float*)d_in[4];   // 18
    float* out = (float*)d_out;

    float*          offbuf = (float*)d_ws;                         // 1,327,104 f
    unsigned short* xt     = (unsigned short*)(offbuf + 1327104);  // 4,718,592 bf16
    unsigned short* wTb    = xt + 4718592;                         // 36,864 bf16
    unsigned short* owTb   = wTb + 36864;                          // 18,432 bf16

    hipLaunchKernelGGL(xcvt_prep,   dim3(1152), dim3(256), 0, stream,
                       x, weight, off_w, xt, wTb, owTb);
    hipLaunchKernelGGL(offs_mfma,   dim3(1152), dim3(256), 0, stream,
                       xt, owTb, off_b, offbuf);
    hipLaunchKernelGGL(deform_main, dim3(1152), dim3(256), 0, stream,
                       xt, wTb, bias, offbuf, out);
}

// Round 9
// 136.369 us; speedup vs baseline: 1.5167x; 1.1967x over previous
//
#include <hip/hip_runtime.h>

#define HH 96
#define WW 96
#define HW 9216
#define NB 8

typedef __bf16 bf16x8 __attribute__((ext_vector_type(8)));
typedef float  f32x4  __attribute__((ext_vector_type(4)));

union BF8 { uint4 u; bf16x8 v; unsigned short s[8]; };

__device__ __forceinline__ unsigned short f2bf_bits(float f) {
    unsigned u = __float_as_uint(f);
    unsigned r = u + 0x7FFFu + ((u >> 16) & 1u);     // RNE
    return (unsigned short)(r >> 16);
}
__device__ __forceinline__ float bf2f(unsigned short s) {
    return __uint_as_float(((unsigned)s) << 16);
}

// bilinear setup: 4 clamped corner base offsets (in shorts) + 4 mask-folded weights
__device__ __forceinline__ void bl_setup(int h, int w, int r, int s, float oy, float ox,
                                         int* a, float* wg) {
    float sy = (float)(h + r) + oy;
    float sx = (float)(w + s) + ox;
    float fy = floorf(sy), fx = floorf(sx);
    int   y0 = (int)fy, x0 = (int)fx;
    int   y1 = y0 + 1, x1 = x0 + 1;
    float wy1 = sy - fy, wx1 = sx - fx;
    float wy0 = 1.f - wy1, wx0 = 1.f - wx1;
    float m00 = (y0 >= 0 && y0 < HH && x0 >= 0 && x0 < WW) ? 1.f : 0.f;
    float m01 = (y0 >= 0 && y0 < HH && x1 >= 0 && x1 < WW) ? 1.f : 0.f;
    float m10 = (y1 >= 0 && y1 < HH && x0 >= 0 && x0 < WW) ? 1.f : 0.f;
    float m11 = (y1 >= 0 && y1 < HH && x1 >= 0 && x1 < WW) ? 1.f : 0.f;
    int cy0 = min(max(y0, 0), HH - 1), cy1 = min(max(y1, 0), HH - 1);
    int cx0 = min(max(x0, 0), WW - 1), cx1 = min(max(x1, 0), WW - 1);
    a[0] = (cy0 * WW + cx0) * 64;  a[1] = (cy0 * WW + cx1) * 64;
    a[2] = (cy1 * WW + cx0) * 64;  a[3] = (cy1 * WW + cx1) * 64;
    wg[0] = wy0 * wx0 * m00;  wg[1] = wy0 * wx1 * m01;
    wg[2] = wy1 * wx0 * m10;  wg[3] = wy1 * wx1 * m11;
}

// ---------------------------------------------------------------------------
// Kernel 1: x NCHW fp32 -> xt NHWC bf16 (LDS transpose, XOR-swizzled, no pad).
// Blocks < 216 also build wTb [tap][co][c] and owTb [j(32)][tap*64+c].
// ---------------------------------------------------------------------------
__global__ __launch_bounds__(256) void xcvt_prep(const float* __restrict__ x,
                                                 const float* __restrict__ weight,
                                                 const float* __restrict__ off_w,
                                                 unsigned short* __restrict__ xt,
                                                 unsigned short* __restrict__ wTb,
                                                 unsigned short* __restrict__ owTb) {
    __shared__ unsigned short T[64 * 64];   // [px][8 chunks], chunk' = chunk ^ (px&7)
    int bid   = blockIdx.x;                 // 1152
    int t     = threadIdx.x;
    int b     = bid & 7;                    // XCD-affine
    int pbase = (bid >> 3) * 64;
    int pl    = t & 63;
    int q     = t >> 6;                     // c-group 0..3 (chunks 2q, 2q+1)

    const float* xp = x + ((size_t)(b * 64 + q * 16)) * HW + pbase + pl;
    unsigned short hb[16];
#pragma unroll
    for (int i = 0; i < 16; ++i) hb[i] = f2bf_bits(xp[(size_t)i * HW]);

    uint4 w0, w1;
    w0.x = hb[0]  | (hb[1]  << 16); w0.y = hb[2]  | (hb[3]  << 16);
    w0.z = hb[4]  | (hb[5]  << 16); w0.w = hb[6]  | (hb[7]  << 16);
    w1.x = hb[8]  | (hb[9]  << 16); w1.y = hb[10] | (hb[11] << 16);
    w1.z = hb[12] | (hb[13] << 16); w1.w = hb[14] | (hb[15] << 16);
    int sw = pl & 7;
    *(uint4*)&T[pl * 64 + (((2 * q)     ^ sw) << 3)] = w0;
    *(uint4*)&T[pl * 64 + (((2 * q + 1) ^ sw) << 3)] = w1;
    __syncthreads();

    int row = t >> 2, rs = row & 7;
    uint4 a  = *(const uint4*)&T[row * 64 + ((((t & 3) * 2)     ^ rs) << 3)];
    uint4 b2 = *(const uint4*)&T[row * 64 + ((((t & 3) * 2 + 1) ^ rs) << 3)];
    unsigned short* dst = xt + ((size_t)(b * HW + pbase)) * 64 + t * 16;
    *(uint4*)dst       = a;
    *(uint4*)(dst + 8) = b2;

    if (bid < 216) {                        // 216*256 = 36864 + 18432
        int i = bid * 256 + t;
        if (i < 36864) {
            int tap = i >> 12;
            int co  = (i >> 6) & 63;
            int c   = i & 63;
            wTb[i] = f2bf_bits(weight[(co * 64 + c) * 9 + tap]);
        } else {
            int f   = i - 36864;
            int j   = f / 576;
            int kk  = f - j * 576;
            int tap = kk >> 6;
            int c   = kk & 63;
            owTb[f] = (j < 18) ? f2bf_bits(off_w[(j * 64 + c) * 9 + tap]) : (unsigned short)0;
        }
    }
}

// ---------------------------------------------------------------------------
// Kernel 2: offset conv. Patch loads lane-contiguous: thread = (pair t>>3,
// chunk t&7); 8 lanes read the 8 chunks of one pixel => 16 line-req/inst.
// ---------------------------------------------------------------------------
__global__ __launch_bounds__(256) void offs_mfma(const unsigned short* __restrict__ xt,
                                                 const unsigned short* __restrict__ owTb,
                                                 const float* __restrict__ ob,
                                                 float* __restrict__ off) {
    __shared__ unsigned short S[64 * 64];   // [px][chunk'], chunk' = chunk ^ (px&7)

    int bid   = blockIdx.x;                 // 1152
    int t     = threadIdx.x;
    int b     = bid & 7;
    int pbase = (bid >> 3) * 64;

    int e    = t & 7;                       // chunk
    int base = t >> 3;                      // 0..31 -> pixels base, base+32
    int px0  = pbase + base;
    int px1  = px0 + 32;
    int h0 = px0 / WW, w0 = px0 - h0 * WW;
    int h1 = px1 / WW, w1 = px1 - h1 * WW;
    int sw = base & 7;                      // (base+32)&7 == base&7

    int ln = t & 15;
    int qd = (t >> 4) & 3;
    int pt = t >> 6;

    f32x4 accj[2] = {{0.f, 0.f, 0.f, 0.f}, {0.f, 0.f, 0.f, 0.f}};
    const unsigned short* xb = xt + (size_t)b * HW * 64;

    for (int tap = 0; tap < 9; ++tap) {
        int r = tap / 3, s = tap - r * 3;

        int  iy0 = h0 - 1 + r, ix0 = w0 - 1 + s;
        bool v0  = (iy0 >= 0) & (iy0 < HH) & (ix0 >= 0) & (ix0 < WW);
        int  a0  = (min(max(iy0, 0), HH - 1) * WW + min(max(ix0, 0), WW - 1)) * 64;
        int  iy1 = h1 - 1 + r, ix1 = w1 - 1 + s;
        bool v1  = (iy1 >= 0) & (iy1 < HH) & (ix1 >= 0) & (ix1 < WW);
        int  a1  = (min(max(iy1, 0), HH - 1) * WW + min(max(ix1, 0), WW - 1)) * 64;

        uint4 p0 = *(const uint4*)(xb + a0 + e * 8);
        uint4 p1 = *(const uint4*)(xb + a1 + e * 8);
        if (!v0) p0 = make_uint4(0, 0, 0, 0);
        if (!v1) p1 = make_uint4(0, 0, 0, 0);
        *(uint4*)&S[base * 64 + ((e ^ sw) << 3)]        = p0;
        *(uint4*)&S[(base + 32) * 64 + ((e ^ sw) << 3)] = p1;
        __syncthreads();

        int  row = pt * 16 + ln, rs = row & 7;
        BF8  fa0, fa1;
        fa0.u = *(const uint4*)&S[row * 64 + ((qd       ^ rs) << 3)];
        fa1.u = *(const uint4*)&S[row * 64 + (((qd + 4) ^ rs) << 3)];
#pragma unroll
        for (int jt = 0; jt < 2; ++jt) {
            const unsigned short* brow = owTb + (size_t)(jt * 16 + ln) * 576 + tap * 64 + qd * 8;
            BF8 fb0, fb1;
            fb0.u = *(const uint4*)brow;
            fb1.u = *(const uint4*)(brow + 32);
            accj[jt] = __builtin_amdgcn_mfma_f32_16x16x32_bf16(fa0.v, fb0.v, accj[jt], 0, 0, 0);
            accj[jt] = __builtin_amdgcn_mfma_f32_16x16x32_bf16(fa1.v, fb1.v, accj[jt], 0, 0, 0);
        }
        __syncthreads();
    }

    // epilogue: D col = j, row = px (quad*4 + reg)
    int pxo = pbase + pt * 16 + qd * 4;
    {
        float bv = ob[ln];
        float4 st;
        st.x = accj[0].x + bv; st.y = accj[0].y + bv;
        st.z = accj[0].z + bv; st.w = accj[0].w + bv;
        *(float4*)(off + ((size_t)(b * 18 + ln)) * HW + pxo) = st;
    }
    if (ln < 2) {
        int   j  = 16 + ln;
        float bv = ob[j];
        float4 st;
        st.x = accj[1].x + bv; st.y = accj[1].y + bv;
        st.z = accj[1].z + bv; st.w = accj[1].w + bv;
        *(float4*)(off + ((size_t)(b * 18 + j)) * HW + pxo) = st;
    }
}

// ---------------------------------------------------------------------------
// Kernel 3: deformable main. Corner loads lane-contiguous (8 lanes = 8 chunks
// of one (pixel,corner) => 16 line-req/inst, was 64). Thread owns all 4
// corners of its (px, chunk) -> bilinear combine in registers -> S (bf16,
// XOR-swizzled LDS). MFMA tiling identical to R4.
// ---------------------------------------------------------------------------
__global__ __launch_bounds__(256) void deform_main(const unsigned short* __restrict__ xt,
                                                   const unsigned short* __restrict__ wTb,
                                                   const float* __restrict__ bias,
                                                   const float* __restrict__ off,
                                                   float* __restrict__ out) {
    __shared__ unsigned short S[64 * 64];   // [px][chunk']
    __shared__ unsigned short Wk[64 * 64];  // [co][chunk']

    int bid   = blockIdx.x;                 // 1152
    int t     = threadIdx.x;
    int b     = bid & 7;
    int pbase = (bid >> 3) * 64;

    int e    = t & 7;                       // chunk
    int base = t >> 3;                      // 0..31 -> pixels base, base+32
    int px0  = pbase + base;
    int px1  = px0 + 32;
    int h0 = px0 / WW, w0 = px0 - h0 * WW;
    int h1 = px1 / WW, w1 = px1 - h1 * WW;
    int sw = base & 7;

    int ln = t & 15;
    int qd = (t >> 4) & 3;
    int ct = t >> 6;                        // wave = co-tile

    const unsigned short* xb = xt + (size_t)b * HW * 64;
    const float* offb = off + (size_t)b * 18 * HW;

    f32x4 acc[4] = {{0.f,0.f,0.f,0.f},{0.f,0.f,0.f,0.f},{0.f,0.f,0.f,0.f},{0.f,0.f,0.f,0.f}};

    // offsets for tap 0 (per-pixel; 8 lanes share an address -> merged req)
    float oy0 = offb[0 * HW + px0], ox0 = offb[1 * HW + px0];
    float oy1 = offb[0 * HW + px1], ox1 = offb[1 * HW + px1];

    for (int tap = 0; tap < 9; ++tap) {
        int r = tap / 3, s = tap - r * 3;

        int   a0[4], a1[4];
        float g0[4], g1[4];
        bl_setup(h0, w0, r, s, oy0, ox0, a0, g0);
        bl_setup(h1, w1, r, s, oy1, ox1, a1, g1);

        // ---- 8 lane-contiguous corner loads ----
        uint4 cA[4], cB[4];
#pragma unroll
        for (int c = 0; c < 4; ++c) cA[c] = *(const uint4*)(xb + a0[c] + e * 8);
#pragma unroll
        for (int c = 0; c < 4; ++c) cB[c] = *(const uint4*)(xb + a1[c] + e * 8);

        // prefetch next tap's offsets while corners are in flight
        float oy0N = 0.f, ox0N = 0.f, oy1N = 0.f, ox1N = 0.f;
        if (tap < 8) {
            oy0N = offb[(2 * tap + 2) * HW + px0]; ox0N = offb[(2 * tap + 3) * HW + px0];
            oy1N = offb[(2 * tap + 2) * HW + px1]; ox1N = offb[(2 * tap + 3) * HW + px1];
        }

        // ---- stage Wk[64co][64ch] for this tap (coalesced, 8 KB) ----
        {
            const uint4* wsrc = (const uint4*)(wTb + (size_t)tap * 4096);
            uint4 wa = wsrc[2 * t];
            uint4 wb = wsrc[2 * t + 1];
            int co = t >> 2, cs = co & 7;
            int c0 = (t & 3) * 2;
            *(uint4*)&Wk[co * 64 + ((c0       ^ cs) << 3)] = wa;
            *(uint4*)&Wk[co * 64 + (((c0 + 1) ^ cs) << 3)] = wb;
        }

        // ---- bilinear combine in registers -> S ----
        {
            BF8 q0, q1, q2, q3;
            q0.u = cA[0]; q1.u = cA[1]; q2.u = cA[2]; q3.u = cA[3];
            unsigned short ov[8];
#pragma unroll
            for (int i = 0; i < 8; ++i) {
                float v = g0[0] * bf2f(q0.s[i]) + g0[1] * bf2f(q1.s[i])
                        + g0[2] * bf2f(q2.s[i]) + g0[3] * bf2f(q3.s[i]);
                ov[i] = f2bf_bits(v);
            }
            uint4 sv;
            sv.x = ov[0] | (ov[1] << 16); sv.y = ov[2] | (ov[3] << 16);
            sv.z = ov[4] | (ov[5] << 16); sv.w = ov[6] | (ov[7] << 16);
            *(uint4*)&S[base * 64 + ((e ^ sw) << 3)] = sv;
        }
        {
            BF8 q0, q1, q2, q3;
            q0.u = cB[0]; q1.u = cB[1]; q2.u = cB[2]; q3.u = cB[3];
            unsigned short ov[8];
#pragma unroll
            for (int i = 0; i < 8; ++i) {
                float v = g1[0] * bf2f(q0.s[i]) + g1[1] * bf2f(q1.s[i])
                        + g1[2] * bf2f(q2.s[i]) + g1[3] * bf2f(q3.s[i]);
                ov[i] = f2bf_bits(v);
            }
            uint4 sv;
            sv.x = ov[0] | (ov[1] << 16); sv.y = ov[2] | (ov[3] << 16);
            sv.z = ov[4] | (ov[5] << 16); sv.w = ov[6] | (ov[7] << 16);
            *(uint4*)&S[(base + 32) * 64 + ((e ^ sw) << 3)] = sv;
        }
        __syncthreads();

        // ---- MFMA: wave ct = co-tile, loops px-tiles ----
        {
            int  wrow = ct * 16 + ln, ws2 = wrow & 7;
            BF8  fb0, fb1;
            fb0.u = *(const uint4*)&Wk[wrow * 64 + ((qd       ^ ws2) << 3)];
            fb1.u = *(const uint4*)&Wk[wrow * 64 + (((qd + 4) ^ ws2) << 3)];
#pragma unroll
            for (int pt = 0; pt < 4; ++pt) {
                int row = pt * 16 + ln, rs = row & 7;
                BF8 fa0, fa1;
                fa0.u = *(const uint4*)&S[row * 64 + ((qd       ^ rs) << 3)];
                fa1.u = *(const uint4*)&S[row * 64 + (((qd + 4) ^ rs) << 3)];
                acc[pt] = __builtin_amdgcn_mfma_f32_16x16x32_bf16(fa0.v, fb0.v, acc[pt], 0, 0, 0);
                acc[pt] = __builtin_amdgcn_mfma_f32_16x16x32_bf16(fa1.v, fb1.v, acc[pt], 0, 0, 0);
            }
        }
        __syncthreads();

        oy0 = oy0N; ox0 = ox0N; oy1 = oy1N; ox1 = ox1N;
    }

    // ---- epilogue: D col=co, rows px = qd*4+reg ----
    int   co = ct * 16 + ln;
    float bv = bias[co];
    float* ob2 = out + ((size_t)(b * 64 + co)) * HW + pbase + qd * 4;
#pragma unroll
    for (int pt = 0; pt < 4; ++pt) {
        float4 st;
        st.x = acc[pt].x + bv; st.y = acc[pt].y + bv;
        st.z = acc[pt].z + bv; st.w = acc[pt].w + bv;
        *(float4*)(ob2 + pt * 16) = st;
    }
}

// ---------------------------------------------------------------------------
extern "C" void kernel_launch(void* const* d_in, const int* in_sizes, int n_in,
                              void* d_out, int out_size, void* d_ws, size_t ws_size,
                              hipStream_t stream) {
    const float* x      = (const float*)d_in[0];   // 8*64*96*96
    const float* weight = (const float*)d_in[1];   // 64*64*3*3
    const float* bias   = (const float*)d_in[2];   // 64
    const float* off_w  = (const float*)d_in[3];   // 18*64*3*3
    const float* off_b  = (const float*)d_in[4];   // 18
    float* out = (float*)d_out;

    float*          offbuf = (float*)d_ws;                         // 1,327,104 f
    unsigned short* xt     = (unsigned short*)(offbuf + 1327104);  // 4,718,592 bf16
    unsigned short* wTb    = xt + 4718592;                         // 36,864 bf16
    unsigned short* owTb   = wTb + 36864;                          // 18,432 bf16

    hipLaunchKernelGGL(xcvt_prep,   dim3(1152), dim3(256), 0, stream,
                       x, weight, off_w, xt, wTb, owTb);
    hipLaunchKernelGGL(offs_mfma,   dim3(1152), dim3(256), 0, stream,
                       xt, owTb, off_b, offbuf);
    hipLaunchKernelGGL(deform_main, dim3(1152), dim3(256), 0, stream,
                       xt, wTb, bias, offbuf, out);
}

// Round 10
// 132.462 us; speedup vs baseline: 1.5614x; 1.0295x over previous
//
#include <hip/hip_runtime.h>
#include <hip/hip_bf16.h>

#define HH 96
#define WW 96
#define HW 9216
#define NB 8

typedef __bf16 bf16x8 __attribute__((ext_vector_type(8)));
typedef float  f32x4  __attribute__((ext_vector_type(4)));

union BF8 { uint4 u; bf16x8 v; unsigned short s[8]; };

__device__ __forceinline__ unsigned short f2bf_bits(float f) {
    unsigned u = __float_as_uint(f);
    unsigned r = u + 0x7FFFu + ((u >> 16) & 1u);     // RNE
    return (unsigned short)(r >> 16);
}
__device__ __forceinline__ float bf2f(unsigned short s) {
    return __uint_as_float(((unsigned)s) << 16);
}
__device__ __forceinline__ unsigned pkbf(float a, float b) {   // v_cvt_pk_bf16_f32
    union { __hip_bfloat162 h; unsigned u; } c;
    c.h = __float22bfloat162_rn(make_float2(a, b));
    return c.u;
}

// bilinear setup: 4 clamped corner base offsets (in shorts) + 4 mask-folded weights
__device__ __forceinline__ void bl_setup(int h, int w, int r, int s, float oy, float ox,
                                         int* a, float* wg) {
    float sy = (float)(h + r) + oy;
    float sx = (float)(w + s) + ox;
    float fy = floorf(sy), fx = floorf(sx);
    int   y0 = (int)fy, x0 = (int)fx;
    int   y1 = y0 + 1, x1 = x0 + 1;
    float wy1 = sy - fy, wx1 = sx - fx;
    float wy0 = 1.f - wy1, wx0 = 1.f - wx1;
    float m00 = (y0 >= 0 && y0 < HH && x0 >= 0 && x0 < WW) ? 1.f : 0.f;
    float m01 = (y0 >= 0 && y0 < HH && x1 >= 0 && x1 < WW) ? 1.f : 0.f;
    float m10 = (y1 >= 0 && y1 < HH && x0 >= 0 && x0 < WW) ? 1.f : 0.f;
    float m11 = (y1 >= 0 && y1 < HH && x1 >= 0 && x1 < WW) ? 1.f : 0.f;
    int cy0 = min(max(y0, 0), HH - 1), cy1 = min(max(y1, 0), HH - 1);
    int cx0 = min(max(x0, 0), WW - 1), cx1 = min(max(x1, 0), WW - 1);
    a[0] = (cy0 * WW + cx0) * 64;  a[1] = (cy0 * WW + cx1) * 64;
    a[2] = (cy1 * WW + cx0) * 64;  a[3] = (cy1 * WW + cx1) * 64;
    wg[0] = wy0 * wx0 * m00;  wg[1] = wy0 * wx1 * m01;
    wg[2] = wy1 * wx0 * m10;  wg[3] = wy1 * wx1 * m11;
}

// ---------------------------------------------------------------------------
// Kernel 1: x NCHW fp32 -> xt NHWC bf16 (LDS transpose, XOR-swizzled).
// Blocks < 216 also build wTb [tap][co][c] and owTb [j(32)][tap*64+c].
// (unchanged from R9 — already near BW floor)
// ---------------------------------------------------------------------------
__global__ __launch_bounds__(256) void xcvt_prep(const float* __restrict__ x,
                                                 const float* __restrict__ weight,
                                                 const float* __restrict__ off_w,
                                                 unsigned short* __restrict__ xt,
                                                 unsigned short* __restrict__ wTb,
                                                 unsigned short* __restrict__ owTb) {
    __shared__ unsigned short T[64 * 64];   // [px][8 chunks], chunk' = chunk ^ (px&7)
    int bid   = blockIdx.x;                 // 1152
    int t     = threadIdx.x;
    int b     = bid & 7;                    // XCD-affine
    int pbase = (bid >> 3) * 64;
    int pl    = t & 63;
    int q     = t >> 6;                     // c-group 0..3 (chunks 2q, 2q+1)

    const float* xp = x + ((size_t)(b * 64 + q * 16)) * HW + pbase + pl;
    unsigned short hb[16];
#pragma unroll
    for (int i = 0; i < 16; ++i) hb[i] = f2bf_bits(xp[(size_t)i * HW]);

    uint4 w0, w1;
    w0.x = hb[0]  | (hb[1]  << 16); w0.y = hb[2]  | (hb[3]  << 16);
    w0.z = hb[4]  | (hb[5]  << 16); w0.w = hb[6]  | (hb[7]  << 16);
    w1.x = hb[8]  | (hb[9]  << 16); w1.y = hb[10] | (hb[11] << 16);
    w1.z = hb[12] | (hb[13] << 16); w1.w = hb[14] | (hb[15] << 16);
    int sw = pl & 7;
    *(uint4*)&T[pl * 64 + (((2 * q)     ^ sw) << 3)] = w0;
    *(uint4*)&T[pl * 64 + (((2 * q + 1) ^ sw) << 3)] = w1;
    __syncthreads();

    int row = t >> 2, rs = row & 7;
    uint4 a  = *(const uint4*)&T[row * 64 + ((((t & 3) * 2)     ^ rs) << 3)];
    uint4 b2 = *(const uint4*)&T[row * 64 + ((((t & 3) * 2 + 1) ^ rs) << 3)];
    unsigned short* dst = xt + ((size_t)(b * HW + pbase)) * 64 + t * 16;
    *(uint4*)dst       = a;
    *(uint4*)(dst + 8) = b2;

    if (bid < 216) {                        // 216*256 = 36864 + 18432
        int i = bid * 256 + t;
        if (i < 36864) {
            int tap = i >> 12;
            int co  = (i >> 6) & 63;
            int c   = i & 63;
            wTb[i] = f2bf_bits(weight[(co * 64 + c) * 9 + tap]);
        } else {
            int f   = i - 36864;
            int j   = f / 576;
            int kk  = f - j * 576;
            int tap = kk >> 6;
            int c   = kk & 63;
            owTb[f] = (j < 18) ? f2bf_bits(off_w[(j * 64 + c) * 9 + tap]) : (unsigned short)0;
        }
    }
}

// ---------------------------------------------------------------------------
// Kernel 2 (fused offs+deform): block = 64 px of one image tile.
// Phase A: zero-padded patch -> S (double-buffered, 1 barrier/tap) -> MFMA
//          vs owTb (B direct from L1) -> offsets into LDS.
// Phase B: bilinear sample (lane-contiguous corner loads, combine in regs,
//          cvt_pk pack) -> S (double-buffered, 1 barrier/tap) -> MFMA vs wTb
//          (B direct from L1). No offbuf round-trip; phase A warms L1 for B.
// ---------------------------------------------------------------------------
__global__ __launch_bounds__(256) void deform_all(const unsigned short* __restrict__ xt,
                                                  const unsigned short* __restrict__ wTb,
                                                  const unsigned short* __restrict__ owTb,
                                                  const float* __restrict__ bias,
                                                  const float* __restrict__ ob,
                                                  float* __restrict__ out) {
    __shared__ unsigned short S[2][64 * 64];   // [buf][px][chunk'], chunk' = chunk ^ (px&7)
    __shared__ float offs[64 * 20];            // [px][18 j + pad]

    int bid   = blockIdx.x;                 // 1152
    int t     = threadIdx.x;
    int b     = bid & 7;                    // image per XCD
    int pbase = (bid >> 3) * 64;

    // staging roles: thread = (pixel-pair base, chunk e)
    int e    = t & 7;
    int base = t >> 3;                      // 0..31 -> pixels base, base+32
    int px0  = pbase + base;
    int px1  = px0 + 32;
    int h0 = px0 / WW, w0 = px0 - h0 * WW;
    int h1 = px1 / WW, w1 = px1 - h1 * WW;
    int sw = base & 7;                      // (base+32)&7 == base&7

    // MFMA roles
    int ln = t & 15;
    int qd = (t >> 4) & 3;
    int wv = t >> 6;                        // wave id: phase A px-tile, phase B co-tile

    const unsigned short* xb = xt + (size_t)b * HW * 64;

    // ================= phase A: offset conv =================
    f32x4 accj[2] = {{0.f, 0.f, 0.f, 0.f}, {0.f, 0.f, 0.f, 0.f}};

    for (int tap = 0; tap < 9; ++tap) {
        int cur = tap & 1;
        int r = tap / 3, s = tap - r * 3;

        int  iy0 = h0 - 1 + r, ix0 = w0 - 1 + s;
        bool v0  = (iy0 >= 0) & (iy0 < HH) & (ix0 >= 0) & (ix0 < WW);
        int  a0  = (min(max(iy0, 0), HH - 1) * WW + min(max(ix0, 0), WW - 1)) * 64;
        int  iy1 = h1 - 1 + r, ix1 = w1 - 1 + s;
        bool v1  = (iy1 >= 0) & (iy1 < HH) & (ix1 >= 0) & (ix1 < WW);
        int  a1  = (min(max(iy1, 0), HH - 1) * WW + min(max(ix1, 0), WW - 1)) * 64;

        uint4 p0 = *(const uint4*)(xb + a0 + e * 8);
        uint4 p1 = *(const uint4*)(xb + a1 + e * 8);
        if (!v0) p0 = make_uint4(0, 0, 0, 0);
        if (!v1) p1 = make_uint4(0, 0, 0, 0);
        *(uint4*)&S[cur][base * 64 + ((e ^ sw) << 3)]        = p0;
        *(uint4*)&S[cur][(base + 32) * 64 + ((e ^ sw) << 3)] = p1;
        __syncthreads();

        int  row = wv * 16 + ln, rs = row & 7;
        BF8  fa0, fa1;
        fa0.u = *(const uint4*)&S[cur][row * 64 + ((qd       ^ rs) << 3)];
        fa1.u = *(const uint4*)&S[cur][row * 64 + (((qd + 4) ^ rs) << 3)];
#pragma unroll
        for (int jt = 0; jt < 2; ++jt) {
            const unsigned short* brow = owTb + (size_t)(jt * 16 + ln) * 576 + tap * 64 + qd * 8;
            BF8 fb0, fb1;
            fb0.u = *(const uint4*)brow;
            fb1.u = *(const uint4*)(brow + 32);
            accj[jt] = __builtin_amdgcn_mfma_f32_16x16x32_bf16(fa0.v, fb0.v, accj[jt], 0, 0, 0);
            accj[jt] = __builtin_amdgcn_mfma_f32_16x16x32_bf16(fa1.v, fb1.v, accj[jt], 0, 0, 0);
        }
        // NOTE: no second barrier — next tap writes the other S buffer; the
        // next tap's barrier orders those writes after this tap's reads.
    }

    // D col=j (ln), row=px (wv*16 + qd*4 + reg) -> offs[px][j]
    {
        int   rowp = wv * 16 + qd * 4;
        float obj = ob[ln];
#pragma unroll
        for (int rg = 0; rg < 4; ++rg) offs[(rowp + rg) * 20 + ln] = accj[0][rg] + obj;
        if (ln < 2) {
            float obj1 = ob[16 + ln];
#pragma unroll
            for (int rg = 0; rg < 4; ++rg) offs[(rowp + rg) * 20 + 16 + ln] = accj[1][rg] + obj1;
        }
    }
    __syncthreads();   // offs visible; also guards S[0] reuse by phase B

    // ================= phase B: deformable conv =================
    f32x4 acc[4] = {{0.f,0.f,0.f,0.f},{0.f,0.f,0.f,0.f},{0.f,0.f,0.f,0.f},{0.f,0.f,0.f,0.f}};

    for (int tap = 0; tap < 9; ++tap) {
        int cur = tap & 1;
        int r = tap / 3, s = tap - r * 3;

        float oy0 = offs[base * 20 + 2 * tap],        ox0 = offs[base * 20 + 2 * tap + 1];
        float oy1 = offs[(base + 32) * 20 + 2 * tap], ox1 = offs[(base + 32) * 20 + 2 * tap + 1];

        int   a0[4], a1[4];
        float g0[4], g1[4];
        bl_setup(h0, w0, r, s, oy0, ox0, a0, g0);
        bl_setup(h1, w1, r, s, oy1, ox1, a1, g1);

        uint4 cA[4], cB[4];
#pragma unroll
        for (int c = 0; c < 4; ++c) cA[c] = *(const uint4*)(xb + a0[c] + e * 8);
#pragma unroll
        for (int c = 0; c < 4; ++c) cB[c] = *(const uint4*)(xb + a1[c] + e * 8);

        // bilinear combine in registers -> bf16 pack (cvt_pk) -> S
        {
            BF8 q0, q1, q2, q3;
            q0.u = cA[0]; q1.u = cA[1]; q2.u = cA[2]; q3.u = cA[3];
            float v[8];
#pragma unroll
            for (int i = 0; i < 8; ++i)
                v[i] = g0[0] * bf2f(q0.s[i]) + g0[1] * bf2f(q1.s[i])
                     + g0[2] * bf2f(q2.s[i]) + g0[3] * bf2f(q3.s[i]);
            uint4 sv;
            sv.x = pkbf(v[0], v[1]); sv.y = pkbf(v[2], v[3]);
            sv.z = pkbf(v[4], v[5]); sv.w = pkbf(v[6], v[7]);
            *(uint4*)&S[cur][base * 64 + ((e ^ sw) << 3)] = sv;
        }
        {
            BF8 q0, q1, q2, q3;
            q0.u = cB[0]; q1.u = cB[1]; q2.u = cB[2]; q3.u = cB[3];
            float v[8];
#pragma unroll
            for (int i = 0; i < 8; ++i)
                v[i] = g1[0] * bf2f(q0.s[i]) + g1[1] * bf2f(q1.s[i])
                     + g1[2] * bf2f(q2.s[i]) + g1[3] * bf2f(q3.s[i]);
            uint4 sv;
            sv.x = pkbf(v[0], v[1]); sv.y = pkbf(v[2], v[3]);
            sv.z = pkbf(v[4], v[5]); sv.w = pkbf(v[6], v[7]);
            *(uint4*)&S[cur][(base + 32) * 64 + ((e ^ sw) << 3)] = sv;
        }
        __syncthreads();

        // MFMA: wave wv = co-tile; B-frags direct from global (L1-hot 8 KB/tap)
        {
            const unsigned short* wb = wTb + (size_t)tap * 4096 + (wv * 16 + ln) * 64 + qd * 8;
            BF8 fb0, fb1;
            fb0.u = *(const uint4*)wb;
            fb1.u = *(const uint4*)(wb + 32);
#pragma unroll
            for (int pt = 0; pt < 4; ++pt) {
                int row = pt * 16 + ln, rs = row & 7;
                BF8 fa0, fa1;
                fa0.u = *(const uint4*)&S[cur][row * 64 + ((qd       ^ rs) << 3)];
                fa1.u = *(const uint4*)&S[cur][row * 64 + (((qd + 4) ^ rs) << 3)];
                acc[pt] = __builtin_amdgcn_mfma_f32_16x16x32_bf16(fa0.v, fb0.v, acc[pt], 0, 0, 0);
                acc[pt] = __builtin_amdgcn_mfma_f32_16x16x32_bf16(fa1.v, fb1.v, acc[pt], 0, 0, 0);
            }
        }
        // no second barrier (double buffer)
    }

    // ---- epilogue: D col=co, rows px = qd*4+reg ----
    int   co = wv * 16 + ln;
    float bv = bias[co];
    float* ob2 = out + ((size_t)(b * 64 + co)) * HW + pbase + qd * 4;
#pragma unroll
    for (int pt = 0; pt < 4; ++pt) {
        float4 st;
        st.x = acc[pt].x + bv; st.y = acc[pt].y + bv;
        st.z = acc[pt].z + bv; st.w = acc[pt].w + bv;
        *(float4*)(ob2 + pt * 16) = st;
    }
}

// ---------------------------------------------------------------------------
extern "C" void kernel_launch(void* const* d_in, const int* in_sizes, int n_in,
                              void* d_out, int out_size, void* d_ws, size_t ws_size,
                              hipStream_t stream) {
    const float* x      = (const float*)d_in[0];   // 8*64*96*96
    const float* weight = (const float*)d_in[1];   // 64*64*3*3
    const float* bias   = (const float*)d_in[2];   // 64
    const float* off_w  = (const float*)d_in[3];   // 18*64*3*3
    const float* off_b  = (const float*)d_in[4];   // 18
    float* out = (float*)d_out;

    unsigned short* xt   = (unsigned short*)d_ws;  // 4,718,592 bf16
    unsigned short* wTb  = xt + 4718592;           // 36,864 bf16
    unsigned short* owTb = wTb + 36864;            // 18,432 bf16

    hipLaunchKernelGGL(xcvt_prep,  dim3(1152), dim3(256), 0, stream,
                       x, weight, off_w, xt, wTb, owTb);
    hipLaunchKernelGGL(deform_all, dim3(1152), dim3(256), 0, stream,
                       xt, wTb, owTb, bias, off_b, out);
}